// Round 1
// baseline (3171.234 us; speedup 1.0000x reference)
//
#include <hip/hip_runtime.h>
#include <math.h>

#define NB 16      // B
#define NT 4096    // T
#define ND 1024    // D
#define NC 64      // C
#define NL 40      // L

#define MAC16(ACC, A4, W4)                                  \
  do {                                                      \
    float _av[4] = {A4.x, A4.y, A4.z, A4.w};                \
    float _wv[4] = {W4.x, W4.y, W4.z, W4.w};                \
    _Pragma("unroll")                                       \
    for (int _i = 0; _i < 4; ++_i)                          \
      _Pragma("unroll")                                     \
      for (int _j = 0; _j < 4; ++_j)                        \
        ACC[_i][_j] += _av[_i] * _wv[_j];                   \
  } while (0)

// h[b][t][c] = sum_d x[b][t][d] * w[c][d] + bias[c]
__global__ __launch_bounds__(256) void wn_start(const float* __restrict__ x,
                                                const float* __restrict__ w,
                                                const float* __restrict__ bias,
                                                float* __restrict__ h) {
  __shared__ __align__(16) float xt[64][68];   // xt[d][t]
  __shared__ __align__(16) float wl[64][68];   // wl[d][c]
  const int tid = threadIdx.x;
  const int blk = blockIdx.x;
  const int b   = blk >> 6;
  const int t0  = (blk & 63) << 6;
  const int tr  = tid >> 4, cr = tid & 15;

  float acc[4][4];
  #pragma unroll
  for (int i = 0; i < 4; ++i)
    #pragma unroll
    for (int j = 0; j < 4; ++j) acc[i][j] = 0.f;

  for (int kc = 0; kc < ND; kc += 64) {
    #pragma unroll
    for (int r = 0; r < 16; ++r) {
      int idx = r * 256 + tid;
      int tl = idx >> 6, dd = idx & 63;
      xt[dd][tl] = x[(size_t)(b * NT + t0 + tl) * ND + kc + dd];
    }
    #pragma unroll
    for (int r = 0; r < 16; ++r) {
      int idx = r * 256 + tid;
      int c = idx >> 6, dd = idx & 63;
      wl[dd][c] = w[c * ND + kc + dd];
    }
    __syncthreads();
    #pragma unroll 16
    for (int k = 0; k < 64; ++k) {
      float4 a  = *(const float4*)&xt[k][tr * 4];
      float4 wv = *(const float4*)&wl[k][cr * 4];
      MAC16(acc, a, wv);
    }
    __syncthreads();
  }
  #pragma unroll
  for (int i = 0; i < 4; ++i) {
    int t = t0 + tr * 4 + i;
    float4 o;
    o.x = acc[i][0] + bias[cr * 4 + 0];
    o.y = acc[i][1] + bias[cr * 4 + 1];
    o.z = acc[i][2] + bias[cr * 4 + 2];
    o.w = acc[i][3] + bias[cr * 4 + 3];
    *(float4*)&h[((size_t)(b * NT + t)) * NC + cr * 4] = o;
  }
}

// One gated WaveNet layer:
// f = tanh(Wd0 h[t-dil] + Wd1 h[t] + bd); g = sigm(Wg0 h[t-dil] + Wg1 h[t] + bg)
// z = f*g; skip += Wsk z + bsk; h_out = Wr z + br + h
__global__ __launch_bounds__(256) void wn_layer(
    const float* __restrict__ h_in, float* __restrict__ h_out,
    float* __restrict__ skip,
    const float* __restrict__ wd, const float* __restrict__ bd,
    const float* __restrict__ wg, const float* __restrict__ bg,
    const float* __restrict__ wr, const float* __restrict__ br,
    const float* __restrict__ wsk, const float* __restrict__ bsk,
    const int dil) {
  __shared__ __align__(16) float ht[64][68];    // ht[cin][t]  (current rows)
  __shared__ __align__(16) float hpt[64][68];   // hprev[cin][t], reused as z[cin][t]
  __shared__ __align__(16) float wb[128][68];   // staged weights [k][cout]
  const int tid = threadIdx.x;
  const int blk = blockIdx.x;
  const int b   = blk >> 6;
  const int t0  = (blk & 63) << 6;
  const int tr  = tid >> 4, cr = tid & 15;
  const float* hbase = h_in + (size_t)b * NT * NC;

  // stage h tiles (transposed)
  #pragma unroll
  for (int r = 0; r < 16; ++r) {
    int idx = r * 256 + tid;
    int tl = idx >> 6, c = idx & 63;
    ht[c][tl] = hbase[(t0 + tl) * NC + c];
    int tp = t0 + tl - dil;
    hpt[c][tl] = (tp >= 0) ? hbase[tp * NC + c] : 0.f;
  }
  // stage dil-conv weights: wb[tap*64+ci][c] = wd[c][ci][tap]
  #pragma unroll
  for (int r = 0; r < 32; ++r) {
    int idx = r * 256 + tid;
    int c = idx >> 7, r2 = idx & 127;
    wb[((r2 & 1) << 6) + (r2 >> 1)][c] = wd[idx];
  }
  __syncthreads();

  float accf[4][4];
  #pragma unroll
  for (int i = 0; i < 4; ++i)
    #pragma unroll
    for (int j = 0; j < 4; ++j) accf[i][j] = 0.f;
  #pragma unroll 16
  for (int k = 0; k < 64; ++k) {
    float4 a  = *(const float4*)&hpt[k][tr * 4];
    float4 wv = *(const float4*)&wb[k][cr * 4];
    MAC16(accf, a, wv);
  }
  #pragma unroll 16
  for (int k = 0; k < 64; ++k) {
    float4 a  = *(const float4*)&ht[k][tr * 4];
    float4 wv = *(const float4*)&wb[64 + k][cr * 4];
    MAC16(accf, a, wv);
  }
  __syncthreads();

  // stage gate weights
  #pragma unroll
  for (int r = 0; r < 32; ++r) {
    int idx = r * 256 + tid;
    int c = idx >> 7, r2 = idx & 127;
    wb[((r2 & 1) << 6) + (r2 >> 1)][c] = wg[idx];
  }
  __syncthreads();

  float accg[4][4];
  #pragma unroll
  for (int i = 0; i < 4; ++i)
    #pragma unroll
    for (int j = 0; j < 4; ++j) accg[i][j] = 0.f;
  #pragma unroll 16
  for (int k = 0; k < 64; ++k) {
    float4 a  = *(const float4*)&hpt[k][tr * 4];
    float4 wv = *(const float4*)&wb[k][cr * 4];
    MAC16(accg, a, wv);
  }
  #pragma unroll 16
  for (int k = 0; k < 64; ++k) {
    float4 a  = *(const float4*)&ht[k][tr * 4];
    float4 wv = *(const float4*)&wb[64 + k][cr * 4];
    MAC16(accg, a, wv);
  }

  // z = tanh(f)*sigmoid(g) -> overwrite hpt as z[cin][t]
  #pragma unroll
  for (int i = 0; i < 4; ++i)
    #pragma unroll
    for (int j = 0; j < 4; ++j) {
      int c = cr * 4 + j;
      float f = tanhf(accf[i][j] + bd[c]);
      float g = accg[i][j] + bg[c];
      g = 1.f / (1.f + expf(-g));
      hpt[c][tr * 4 + i] = f * g;
    }
  __syncthreads();   // waits accg wb-reads AND publishes z

  // stage skip/res weights: wb[ci][c] = wsk[c][ci]; wb[64+ci][c] = wr[c][ci]
  #pragma unroll
  for (int r = 0; r < 16; ++r) {
    int idx = r * 256 + tid;
    int c = idx >> 6, ci = idx & 63;
    wb[ci][c]      = wsk[idx];
    wb[64 + ci][c] = wr[idx];
  }
  __syncthreads();

  float accs[4][4], accr[4][4];
  #pragma unroll
  for (int i = 0; i < 4; ++i)
    #pragma unroll
    for (int j = 0; j < 4; ++j) { accs[i][j] = 0.f; accr[i][j] = 0.f; }
  #pragma unroll 16
  for (int k = 0; k < 64; ++k) {
    float4 a   = *(const float4*)&hpt[k][tr * 4];
    float4 wv  = *(const float4*)&wb[k][cr * 4];
    float4 wv2 = *(const float4*)&wb[64 + k][cr * 4];
    MAC16(accs, a, wv);
    MAC16(accr, a, wv2);
  }

  // epilogue: skip += accs + bsk ; h_out = accr + br + h_in
  #pragma unroll
  for (int i = 0; i < 4; ++i) {
    int t = t0 + tr * 4 + i;
    size_t off = ((size_t)b * NT + t) * NC + cr * 4;
    float4 sk = *(const float4*)&skip[off];
    float4 so, ho;
    so.x = sk.x + accs[i][0] + bsk[cr * 4 + 0];
    so.y = sk.y + accs[i][1] + bsk[cr * 4 + 1];
    so.z = sk.z + accs[i][2] + bsk[cr * 4 + 2];
    so.w = sk.w + accs[i][3] + bsk[cr * 4 + 3];
    *(float4*)&skip[off] = so;
    ho.x = accr[i][0] + br[cr * 4 + 0] + ht[cr * 4 + 0][tr * 4 + i];
    ho.y = accr[i][1] + br[cr * 4 + 1] + ht[cr * 4 + 1][tr * 4 + i];
    ho.z = accr[i][2] + br[cr * 4 + 2] + ht[cr * 4 + 2][tr * 4 + i];
    ho.w = accr[i][3] + br[cr * 4 + 3] + ht[cr * 4 + 3][tr * 4 + i];
    *(float4*)&h_out[off] = ho;
  }
}

// end head: s=relu(skip); e1=relu(W1 s+b1); e2=W2 e1+b2; acc[b][k] += e2
__global__ __launch_bounds__(256) void wn_end(const float* __restrict__ skip,
                                              const float* __restrict__ w1,
                                              const float* __restrict__ b1,
                                              const float* __restrict__ w2,
                                              const float* __restrict__ b2,
                                              float* __restrict__ acc_out) {
  __shared__ __align__(16) float we1[64][64];
  __shared__ __align__(16) float we2[4][64];
  __shared__ float bb1[64];
  __shared__ float red[4][4];
  const int tid = threadIdx.x;
  const int blk = blockIdx.x;
  const int b = blk >> 4;
  const int t = ((blk & 15) << 8) + tid;

  float* we1f = &we1[0][0];
  #pragma unroll
  for (int r = 0; r < 16; ++r) we1f[r * 256 + tid] = w1[r * 256 + tid];
  (&we2[0][0])[tid] = w2[tid];
  if (tid < 64) bb1[tid] = b1[tid];
  __syncthreads();

  float s[64];
  const float* srow = skip + ((size_t)b * NT + t) * NC;
  #pragma unroll
  for (int q = 0; q < 16; ++q) {
    float4 v = *(const float4*)&srow[q * 4];
    s[4 * q + 0] = fmaxf(v.x, 0.f);
    s[4 * q + 1] = fmaxf(v.y, 0.f);
    s[4 * q + 2] = fmaxf(v.z, 0.f);
    s[4 * q + 3] = fmaxf(v.w, 0.f);
  }
  float e2[4] = {b2[0], b2[1], b2[2], b2[3]};
  #pragma unroll
  for (int c = 0; c < 64; ++c) {
    float acc = bb1[c];
    #pragma unroll
    for (int q = 0; q < 16; ++q) {
      float4 w4 = *(const float4*)&we1[c][q * 4];
      acc += w4.x * s[4 * q + 0] + w4.y * s[4 * q + 1] +
             w4.z * s[4 * q + 2] + w4.w * s[4 * q + 3];
    }
    float e1 = fmaxf(acc, 0.f);
    e2[0] += we2[0][c] * e1;
    e2[1] += we2[1][c] * e1;
    e2[2] += we2[2][c] * e1;
    e2[3] += we2[3][c] * e1;
  }
  const int lane = tid & 63, wv = tid >> 6;
  #pragma unroll
  for (int k = 0; k < 4; ++k) {
    float v = e2[k];
    #pragma unroll
    for (int off = 32; off > 0; off >>= 1) v += __shfl_down(v, off, 64);
    if (lane == 0) red[wv][k] = v;
  }
  __syncthreads();
  if (tid == 0) {
    #pragma unroll
    for (int k = 0; k < 4; ++k) {
      float sum = red[0][k] + red[1][k] + red[2][k] + red[3][k];
      atomicAdd(&acc_out[b * 4 + k], sum);
    }
  }
}

__global__ void wn_final(const float* __restrict__ acc, float* __restrict__ out) {
  const int tid = threadIdx.x;
  if (tid < 64) {
    const int b = tid >> 2, j = tid & 3;
    float v = acc[b * 4 + j] / (float)NT;
    float r;
    if (j == 0)      r = v;
    else if (j == 2) r = 1.f / (1.f + expf(-v));
    else             r = (v > 20.f) ? v : log1pf(expf(v));
    out[j * 16 + b] = r;
  }
}

extern "C" void kernel_launch(void* const* d_in, const int* in_sizes, int n_in,
                              void* d_out, int out_size, void* d_ws, size_t ws_size,
                              hipStream_t stream) {
  const float* x       = (const float*)d_in[0];
  const float* w_start = (const float*)d_in[1];
  const float* b_start = (const float*)d_in[2];
  const float* w_dil   = (const float*)d_in[3];
  const float* b_dil   = (const float*)d_in[4];
  const float* w_gate  = (const float*)d_in[5];
  const float* b_gate  = (const float*)d_in[6];
  const float* w_res   = (const float*)d_in[7];
  const float* b_res   = (const float*)d_in[8];
  const float* w_skip  = (const float*)d_in[9];
  const float* b_skip  = (const float*)d_in[10];
  const float* w_end1  = (const float*)d_in[11];
  const float* b_end1  = (const float*)d_in[12];
  const float* w_end2  = (const float*)d_in[13];
  const float* b_end2  = (const float*)d_in[14];
  float* out = (float*)d_out;

  char* ws = (char*)d_ws;
  const size_t HBYTES = (size_t)NB * NT * NC * sizeof(float);  // 16 MB
  float* hA   = (float*)(ws);
  float* hB   = (float*)(ws + HBYTES);
  float* skip = (float*)(ws + 2 * HBYTES);
  float* accb = (float*)(ws + 3 * HBYTES);

  hipMemsetAsync(skip, 0, HBYTES, stream);
  hipMemsetAsync(accb, 0, 64 * sizeof(float), stream);

  wn_start<<<NB * (NT / 64), 256, 0, stream>>>(x, w_start, b_start, hA);

  float* hin = hA;
  float* hout = hB;
  for (int l = 0; l < NL; ++l) {
    int dil = 1 << (l % 10);
    wn_layer<<<NB * (NT / 64), 256, 0, stream>>>(
        hin, hout, skip,
        w_dil  + (size_t)l * NC * NC * 2, b_dil  + l * NC,
        w_gate + (size_t)l * NC * NC * 2, b_gate + l * NC,
        w_res  + (size_t)l * NC * NC,     b_res  + l * NC,
        w_skip + (size_t)l * NC * NC,     b_skip + l * NC,
        dil);
    float* tmp = hin; hin = hout; hout = tmp;
  }

  wn_end<<<NB * (NT / 256), 256, 0, stream>>>(skip, w_end1, b_end1, w_end2, b_end2, accb);
  wn_final<<<1, 64, 0, stream>>>(accb, out);
}

// Round 2
// 1295.071 us; speedup vs baseline: 2.4487x; 2.4487x over previous
//
#include <hip/hip_runtime.h>
#include <math.h>

#define NB 16      // B
#define NT 4096    // T
#define ND 1024    // D
#define NC 64      // C
#define NL 40      // L

typedef short short8 __attribute__((ext_vector_type(8)));   // 8 bf16 (4 VGPR)
typedef float f32x4  __attribute__((ext_vector_type(4)));   // MFMA acc

__device__ __forceinline__ unsigned short f2bf(float x) {
  union { float f; unsigned u; } v; v.f = x;
  unsigned r = v.u + 0x7FFFu + ((v.u >> 16) & 1u);   // RNE
  return (unsigned short)(r >> 16);
}

// load 8 consecutive floats at p (16B-aligned) -> bf16x8 frag
__device__ __forceinline__ short8 load_cvt8(const float* p) {
  float4 a = *(const float4*)p;
  float4 b = *(const float4*)(p + 4);
  short8 r;
  r[0] = (short)f2bf(a.x); r[1] = (short)f2bf(a.y);
  r[2] = (short)f2bf(a.z); r[3] = (short)f2bf(a.w);
  r[4] = (short)f2bf(b.x); r[5] = (short)f2bf(b.y);
  r[6] = (short)f2bf(b.z); r[7] = (short)f2bf(b.w);
  return r;
}

// ---------------------------------------------------------------------------
// Weight prep: fp32 -> bf16, arranged in exact MFMA B-fragment order.
// Global frag order fg:
//   fg <  128           : start conv,  fg = n*32 + s          (K=1024, 32 ksteps)
//   fg >= 128           : per layer l (48 frags):
//     r = 0..15  : f    (dil conv)  r = n*4 + (p*2+ks)
//     r = 16..31 : g    (gate conv)
//     r = 32..39 : skip             r = 32 + n*2 + s
//     r = 40..47 : res              r = 40 + n*2 + s
// Element: pw[fg*512 + lane*8 + j]; B-frag(col=lane&15 -> cout, k=(lane>>4)*8+j)
// ---------------------------------------------------------------------------
__global__ __launch_bounds__(256) void wn_prep(
    const float* __restrict__ wst, const float* __restrict__ wd,
    const float* __restrict__ wg,  const float* __restrict__ wr,
    const float* __restrict__ wsk, short8* __restrict__ pw) {
  const int tid  = blockIdx.x * 256 + threadIdx.x;   // 0..131071
  const int lane = tid & 63;
  const int fg   = tid >> 6;
  const int rlo  = lane & 15, kg = lane >> 4;
  float v[8];
  if (fg < 128) {
    const int n = fg >> 5, s = fg & 31;
    const int c = n * 16 + rlo;
    const int d0 = s * 32 + kg * 8;
    #pragma unroll
    for (int j = 0; j < 8; ++j) v[j] = wst[c * ND + d0 + j];
  } else {
    const int fg2 = fg - 128;
    const int l = fg2 / 48, r = fg2 % 48;
    const int c = ((r < 32 ? (r & 15) : (r - 32) & 7) >> (r < 32 ? 2 : 1)) * 16 + rlo;
    if (r < 32) {
      const int r2 = r & 15;
      const int s4 = r2 & 3, p = s4 >> 1, ks = s4 & 1;
      const int ci0 = ks * 32 + kg * 8;
      const float* src = (r >= 16) ? wg : wd;
      #pragma unroll
      for (int j = 0; j < 8; ++j)
        v[j] = src[(size_t)((l * NC + c) * NC + ci0 + j) * 2 + p];
    } else {
      const int r2 = (r - 32) & 7;
      const int s = r2 & 1;
      const int ci0 = s * 32 + kg * 8;
      const float* src = (r >= 40) ? wr : wsk;
      #pragma unroll
      for (int j = 0; j < 8; ++j)
        v[j] = src[(size_t)(l * NC + c) * NC + ci0 + j];
    }
  }
  short8 o;
  #pragma unroll
  for (int j = 0; j < 8; ++j) o[j] = (short)f2bf(v[j]);
  pw[(size_t)fg * 64 + lane] = o;
}

// ---------------------------------------------------------------------------
// Start conv via MFMA: h[b][t][c] = sum_d x[b][t][d] * w[c][d] + bias[c]
// Block 256 = 4 waves; wave w owns t-rows [t0+16w, +16) x all 64 cout.
// ---------------------------------------------------------------------------
__global__ __launch_bounds__(256) void wn_start(
    const float* __restrict__ x, const short8* __restrict__ pw,
    const float* __restrict__ bias, float* __restrict__ h) {
  const int tid = threadIdx.x, lane = tid & 63, w = tid >> 6;
  const int blk = blockIdx.x, b = blk >> 6, t0 = (blk & 63) << 6;
  const int rlo = lane & 15, kg = lane >> 4;
  const size_t bT = (size_t)b * NT;
  const int trow = t0 + 16 * w + rlo;
  const float* xr = x + (bT + trow) * ND + kg * 8;

  f32x4 acc[4];
  #pragma unroll
  for (int n = 0; n < 4; ++n) acc[n] = (f32x4)0.f;

  for (int s = 0; s < 32; ++s) {
    short8 a = load_cvt8(xr + s * 32);
    #pragma unroll
    for (int n = 0; n < 4; ++n)
      acc[n] = __builtin_amdgcn_mfma_f32_16x16x32_bf16(
          a, pw[(size_t)(n * 32 + s) * 64 + lane], acc[n], 0, 0, 0);
  }
  #pragma unroll
  for (int n = 0; n < 4; ++n) {
    const int c = n * 16 + rlo;
    const float bv = bias[c];
    #pragma unroll
    for (int i = 0; i < 4; ++i) {
      const int t = t0 + 16 * w + kg * 4 + i;
      h[(bT + t) * NC + c] = acc[n][i] + bv;
    }
  }
}

// ---------------------------------------------------------------------------
// One gated layer, MFMA. No __syncthreads: z transpose is wave-private LDS.
// ---------------------------------------------------------------------------
__global__ __launch_bounds__(256) void wn_layer(
    const float* __restrict__ h_in, float* __restrict__ h_out,
    float* __restrict__ skip, const short8* __restrict__ pw, const int fgbase,
    const float* __restrict__ bd, const float* __restrict__ bg,
    const float* __restrict__ br, const float* __restrict__ bsk,
    const int dil) {
  __shared__ __align__(16) unsigned short zsh[64 * 64];  // [t_local][cin], swizzled
  const int tid = threadIdx.x, lane = tid & 63, w = tid >> 6;
  const int blk = blockIdx.x, b = blk >> 6, t0 = (blk & 63) << 6;
  const int rlo = lane & 15, kg = lane >> 4;
  const size_t bT = (size_t)b * NT;
  const int trow = t0 + 16 * w + rlo;

  // A-frags: current rows (tap1) and dilated-past rows (tap0), 2 ksteps each
  short8 ac[2], ap[2];
  {
    const float* rp = h_in + (bT + trow) * NC + kg * 8;
    ac[0] = load_cvt8(rp);
    ac[1] = load_cvt8(rp + 32);
    const int tp = trow - dil;
    if (tp >= 0) {
      const float* rq = h_in + (bT + tp) * NC + kg * 8;
      ap[0] = load_cvt8(rq);
      ap[1] = load_cvt8(rq + 32);
    } else {
      ap[0] = (short8)0; ap[1] = (short8)0;
    }
  }

  // f/g convs: K = 128 (2 taps x 64 cin), 4 ksteps of 32
  f32x4 accf[4], accg[4];
  #pragma unroll
  for (int n = 0; n < 4; ++n) { accf[n] = (f32x4)0.f; accg[n] = (f32x4)0.f; }
  const short8* pwf = pw + (size_t)fgbase * 64;
  const short8* pwg = pw + (size_t)(fgbase + 16) * 64;
  #pragma unroll
  for (int n = 0; n < 4; ++n) {
    #pragma unroll
    for (int s4 = 0; s4 < 4; ++s4) {
      short8 a = (s4 >> 1) ? ac[s4 & 1] : ap[s4 & 1];  // p=0 -> t-dil, p=1 -> t
      accf[n] = __builtin_amdgcn_mfma_f32_16x16x32_bf16(
          a, pwf[(size_t)(n * 4 + s4) * 64 + lane], accf[n], 0, 0, 0);
      accg[n] = __builtin_amdgcn_mfma_f32_16x16x32_bf16(
          a, pwg[(size_t)(n * 4 + s4) * 64 + lane], accg[n], 0, 0, 0);
    }
  }

  // z = tanh(f+bd)*sigmoid(g+bg), write bf16 into swizzled LDS [t][c]
  char* zb = (char*)zsh;
  #pragma unroll
  for (int n = 0; n < 4; ++n) {
    const int c = n * 16 + rlo;
    const float bdv = bd[c], bgv = bg[c];
    #pragma unroll
    for (int i = 0; i < 4; ++i) {
      const int row = 16 * w + kg * 4 + i;
      float fv = accf[n][i] + bdv;
      fv = fminf(fmaxf(fv, -20.f), 20.f);
      const float e2 = __expf(2.f * fv);
      const float tf = (e2 - 1.f) / (e2 + 1.f);
      float gv = accg[n][i] + bgv;
      gv = fminf(fmaxf(gv, -20.f), 20.f);
      const float sg = 1.f / (1.f + __expf(-gv));
      const int bo = (row * 128 + c * 2) ^ ((row & 7) << 4);
      *(unsigned short*)(zb + bo) = f2bf(tf * sg);
    }
  }

  // read z A-frags back (wave-private rows; DS in-order per wave, no barrier)
  short8 az[2];
  #pragma unroll
  for (int s = 0; s < 2; ++s) {
    const int row = 16 * w + rlo;
    const int bo = (row * 128 + kg * 16 + s * 64) ^ ((row & 7) << 4);
    az[s] = *(const short8*)(zb + bo);
  }

  // skip/res convs: K = 64, 2 ksteps
  f32x4 accs[4], accr[4];
  #pragma unroll
  for (int n = 0; n < 4; ++n) { accs[n] = (f32x4)0.f; accr[n] = (f32x4)0.f; }
  const short8* pws = pw + (size_t)(fgbase + 32) * 64;
  const short8* pwr = pw + (size_t)(fgbase + 40) * 64;
  #pragma unroll
  for (int n = 0; n < 4; ++n) {
    #pragma unroll
    for (int s = 0; s < 2; ++s) {
      accs[n] = __builtin_amdgcn_mfma_f32_16x16x32_bf16(
          az[s], pws[(size_t)(n * 2 + s) * 64 + lane], accs[n], 0, 0, 0);
      accr[n] = __builtin_amdgcn_mfma_f32_16x16x32_bf16(
          az[s], pwr[(size_t)(n * 2 + s) * 64 + lane], accr[n], 0, 0, 0);
    }
  }

  // epilogue (fp32 carry paths)
  #pragma unroll
  for (int n = 0; n < 4; ++n) {
    const int c = n * 16 + rlo;
    const float bsv = bsk[c], brv = br[c];
    #pragma unroll
    for (int i = 0; i < 4; ++i) {
      const int t = t0 + 16 * w + kg * 4 + i;
      const size_t off = (bT + t) * NC + c;
      skip[off] += accs[n][i] + bsv;
      h_out[off] = accr[n][i] + brv + h_in[off];
    }
  }
}

// end head: s=relu(skip); e1=relu(W1 s+b1); e2=W2 e1+b2; acc[b][k] += e2
__global__ __launch_bounds__(256) void wn_end(const float* __restrict__ skip,
                                              const float* __restrict__ w1,
                                              const float* __restrict__ b1,
                                              const float* __restrict__ w2,
                                              const float* __restrict__ b2,
                                              float* __restrict__ acc_out) {
  __shared__ __align__(16) float we1[64][64];
  __shared__ __align__(16) float we2[4][64];
  __shared__ float bb1[64];
  __shared__ float red[4][4];
  const int tid = threadIdx.x;
  const int blk = blockIdx.x;
  const int b = blk >> 4;
  const int t = ((blk & 15) << 8) + tid;

  float* we1f = &we1[0][0];
  #pragma unroll
  for (int r = 0; r < 16; ++r) we1f[r * 256 + tid] = w1[r * 256 + tid];
  (&we2[0][0])[tid] = w2[tid];
  if (tid < 64) bb1[tid] = b1[tid];
  __syncthreads();

  float s[64];
  const float* srow = skip + ((size_t)b * NT + t) * NC;
  #pragma unroll
  for (int q = 0; q < 16; ++q) {
    float4 v = *(const float4*)&srow[q * 4];
    s[4 * q + 0] = fmaxf(v.x, 0.f);
    s[4 * q + 1] = fmaxf(v.y, 0.f);
    s[4 * q + 2] = fmaxf(v.z, 0.f);
    s[4 * q + 3] = fmaxf(v.w, 0.f);
  }
  float e2[4] = {b2[0], b2[1], b2[2], b2[3]};
  #pragma unroll
  for (int c = 0; c < 64; ++c) {
    float acc = bb1[c];
    #pragma unroll
    for (int q = 0; q < 16; ++q) {
      float4 w4 = *(const float4*)&we1[c][q * 4];
      acc += w4.x * s[4 * q + 0] + w4.y * s[4 * q + 1] +
             w4.z * s[4 * q + 2] + w4.w * s[4 * q + 3];
    }
    float e1 = fmaxf(acc, 0.f);
    e2[0] += we2[0][c] * e1;
    e2[1] += we2[1][c] * e1;
    e2[2] += we2[2][c] * e1;
    e2[3] += we2[3][c] * e1;
  }
  const int lane = tid & 63, wv = tid >> 6;
  #pragma unroll
  for (int k = 0; k < 4; ++k) {
    float v = e2[k];
    #pragma unroll
    for (int off = 32; off > 0; off >>= 1) v += __shfl_down(v, off, 64);
    if (lane == 0) red[wv][k] = v;
  }
  __syncthreads();
  if (tid == 0) {
    #pragma unroll
    for (int k = 0; k < 4; ++k) {
      float sum = red[0][k] + red[1][k] + red[2][k] + red[3][k];
      atomicAdd(&acc_out[b * 4 + k], sum);
    }
  }
}

__global__ void wn_final(const float* __restrict__ acc, float* __restrict__ out) {
  const int tid = threadIdx.x;
  if (tid < 64) {
    const int b = tid >> 2, j = tid & 3;
    float v = acc[b * 4 + j] / (float)NT;
    float r;
    if (j == 0)      r = v;
    else if (j == 2) r = 1.f / (1.f + expf(-v));
    else             r = (v > 20.f) ? v : log1pf(expf(v));
    out[j * 16 + b] = r;
  }
}

extern "C" void kernel_launch(void* const* d_in, const int* in_sizes, int n_in,
                              void* d_out, int out_size, void* d_ws, size_t ws_size,
                              hipStream_t stream) {
  const float* x       = (const float*)d_in[0];
  const float* w_start = (const float*)d_in[1];
  const float* b_start = (const float*)d_in[2];
  const float* w_dil   = (const float*)d_in[3];
  const float* b_dil   = (const float*)d_in[4];
  const float* w_gate  = (const float*)d_in[5];
  const float* b_gate  = (const float*)d_in[6];
  const float* w_res   = (const float*)d_in[7];
  const float* b_res   = (const float*)d_in[8];
  const float* w_skip  = (const float*)d_in[9];
  const float* b_skip  = (const float*)d_in[10];
  const float* w_end1  = (const float*)d_in[11];
  const float* b_end1  = (const float*)d_in[12];
  const float* w_end2  = (const float*)d_in[13];
  const float* b_end2  = (const float*)d_in[14];
  float* out = (float*)d_out;

  char* ws = (char*)d_ws;
  const size_t HBYTES = (size_t)NB * NT * NC * sizeof(float);  // 16 MB
  float*  hA   = (float*)(ws);
  float*  hB   = (float*)(ws + HBYTES);
  float*  skip = (float*)(ws + 2 * HBYTES);
  float*  accb = (float*)(ws + 3 * HBYTES);
  short8* pw   = (short8*)(ws + 3 * HBYTES + 4096);  // 2 MB bf16 frag table

  hipMemsetAsync(skip, 0, HBYTES, stream);
  hipMemsetAsync(accb, 0, 64 * sizeof(float), stream);

  wn_prep<<<512, 256, 0, stream>>>(w_start, w_dil, w_gate, w_res, w_skip, pw);
  wn_start<<<NB * (NT / 64), 256, 0, stream>>>(x, pw, b_start, hA);

  float* hin = hA;
  float* hout = hB;
  for (int l = 0; l < NL; ++l) {
    int dil = 1 << (l % 10);
    wn_layer<<<NB * (NT / 64), 256, 0, stream>>>(
        hin, hout, skip, pw, 128 + l * 48,
        b_dil + l * NC, b_gate + l * NC, b_res + l * NC, b_skip + l * NC, dil);
    float* tmp = hin; hin = hout; hout = tmp;
  }

  wn_end<<<NB * (NT / 256), 256, 0, stream>>>(skip, w_end1, b_end1, w_end2, b_end2, accb);
  wn_final<<<1, 64, 0, stream>>>(accb, out);
}